// Round 1
// baseline (2705.915 us; speedup 1.0000x reference)
//
#include <hip/hip_runtime.h>

typedef unsigned int uint;
typedef unsigned short ushort;
using short8 = __attribute__((ext_vector_type(8))) short;
using f32x4  = __attribute__((ext_vector_type(4))) float;

#define DEVFN __device__ __forceinline__

constexpr int B_ = 32, T_ = 128, E_ = 256, H_ = 512, A_ = 256, V_ = 32000, S_ = 64;
constexpr int G3_ = 3 * H_;          // 1536
constexpr int OUTIN_ = E_ + 4 * H_;  // 2304
constexpr int M_ = B_ * T_;          // 4096 rows, convention row = t*32 + b

DEVFN ushort f2b(float f) {  // f32 -> bf16 RNE
  uint u = __float_as_uint(f);
  u += 0x7fffu + ((u >> 16) & 1u);
  return (ushort)(u >> 16);
}
DEVFN float sigmoid_f(float x) { return 1.f / (1.f + __expf(-x)); }
DEVFN float tanh_f(float x) { float e = __expf(2.f * x); return 1.f - 2.f / (e + 1.f); }

// ---------------- transpose + convert: in f32 (R x C) -> out bf16 (C x R) ----------------
__global__ __launch_bounds__(256) void transpose_k(const float* __restrict__ in,
                                                   ushort* __restrict__ out, int R, int C) {
  __shared__ __align__(16) ushort tile[64][65];
  int c0 = blockIdx.x * 64, r0 = blockIdx.y * 64;
  int tx = threadIdx.x & 63, ty = threadIdx.x >> 6;
#pragma unroll
  for (int k = 0; k < 16; k++) {
    int i = ty + k * 4;
    int r = r0 + i, c = c0 + tx;
    if (r < R && c < C) tile[tx][i] = f2b(in[(size_t)r * C + c]);
  }
  __syncthreads();
#pragma unroll
  for (int k = 0; k < 16; k++) {
    int j = ty + k * 4;
    int c = c0 + j, r = r0 + tx;
    if (r < R && c < C) out[(size_t)c * R + r] = tile[j][tx];
  }
}

__global__ void convert_k(const float* __restrict__ in, ushort* __restrict__ out, int n) {
  int i = blockIdx.x * 256 + threadIdx.x;
  if (i < n) out[i] = f2b(in[i]);
}

// ---------------- embedding gather -> bf16, rows r = t*32+b ----------------
__global__ __launch_bounds__(256) void gather_k(const int* __restrict__ tokens,
                                                const float* __restrict__ emb,
                                                ushort* __restrict__ xbf) {
  int r = blockIdx.x;
  int t = r >> 5, b = r & 31;
  int tok = tokens[b * T_ + t];
  xbf[(size_t)r * E_ + threadIdx.x] = f2b(emb[(size_t)tok * E_ + threadIdx.x]);
}

// ---------------- kq[b][a] = knowledge[b] @ wq[E+H: E+2H] + bq ----------------
__global__ __launch_bounds__(256) void kq_k(const float* __restrict__ knowledge,
                                            const float* __restrict__ wq,
                                            const float* __restrict__ bq,
                                            float* __restrict__ kq) {
  int b = blockIdx.x, a = threadIdx.x;
  const float* kn = knowledge + b * H_;
  float s = 0.f;
  for (int h = 0; h < H_; h++) s += kn[h] * wq[(size_t)(E_ + H_ + h) * A_ + a];
  kq[b * A_ + a] = s + bq[a];
}

// ---------------- generic bf16 MFMA GEMM: C = A (MxK) * Bt^T (Bt is N x K) + bias ----------------
template <int OUTBF, int PERM, int HASBIAS>
__global__ __launch_bounds__(256) void gemm_bt(const ushort* __restrict__ Ag,
                                               const ushort* __restrict__ Btg,
                                               const float* __restrict__ bias,
                                               void* __restrict__ Cg, int M, int N, int K) {
  __shared__ __align__(16) ushort Ash[128][40];
  __shared__ __align__(16) ushort Bsh[128][40];
  const int m0 = blockIdx.y * 128, n0 = blockIdx.x * 128;
  const int tid = threadIdx.x;
  const int wave = tid >> 6, lane = tid & 63, lr = lane & 15, lg = lane >> 4;
  const int wr = wave >> 1, wc = wave & 1;
  f32x4 acc[4][4] = {};
  for (int kk = 0; kk < K; kk += 32) {
    {
      int r = tid >> 2, q = tid & 3;
      *(short8*)&Ash[r][q * 8] = *(const short8*)&Ag[(size_t)(m0 + r) * K + kk + q * 8];
      *(short8*)&Bsh[r][q * 8] = *(const short8*)&Btg[(size_t)(n0 + r) * K + kk + q * 8];
      r += 64;
      *(short8*)&Ash[r][q * 8] = *(const short8*)&Ag[(size_t)(m0 + r) * K + kk + q * 8];
      *(short8*)&Bsh[r][q * 8] = *(const short8*)&Btg[(size_t)(n0 + r) * K + kk + q * 8];
    }
    __syncthreads();
    short8 af[4], bfr[4];
#pragma unroll
    for (int mi = 0; mi < 4; mi++) af[mi] = *(const short8*)&Ash[wr * 64 + mi * 16 + lr][lg * 8];
#pragma unroll
    for (int ni = 0; ni < 4; ni++) bfr[ni] = *(const short8*)&Bsh[wc * 64 + ni * 16 + lr][lg * 8];
#pragma unroll
    for (int mi = 0; mi < 4; mi++)
#pragma unroll
      for (int ni = 0; ni < 4; ni++)
        acc[mi][ni] = __builtin_amdgcn_mfma_f32_16x16x32_bf16(af[mi], bfr[ni], acc[mi][ni], 0, 0, 0);
    __syncthreads();
  }
#pragma unroll
  for (int mi = 0; mi < 4; mi++)
#pragma unroll
    for (int ni = 0; ni < 4; ni++) {
      int col = n0 + wc * 64 + ni * 16 + lr;
      float bv = HASBIAS ? bias[col] : 0.f;
#pragma unroll
      for (int r = 0; r < 4; r++) {
        int row = m0 + wr * 64 + mi * 16 + lg * 4 + r;
        int orow = PERM ? ((row & 31) << 7) + (row >> 5) : row;  // t*32+b -> b*128+t
        float v = acc[mi][ni][r] + bv;
        if (OUTBF) ((ushort*)Cg)[(size_t)orow * N + col] = f2b(v);
        else       ((float*)Cg)[(size_t)orow * N + col] = v;
      }
    }
}

// ---------------- init h state slab 0 ----------------
__global__ void inith_k(const float* __restrict__ h0, float* __restrict__ hpf,
                        ushort* __restrict__ hpb) {
  int g = blockIdx.x * 256 + threadIdx.x;  // < B_*H_
  float v = h0[g];
  hpf[g] = v;
  hpb[g] = f2b(v);
}

// ---------------- persistent GRU scan: 32 WGs x 128 threads, WG owns 16 h-cols ----------------
__global__ __launch_bounds__(128, 1) void scan_k(
    const float* __restrict__ w_hh, const float* __restrict__ b_hh,
    const float* __restrict__ gi, const int* __restrict__ lengths,
    float* __restrict__ hpf, ushort* hpb, float* __restrict__ hnew,
    float* __restrict__ hidmem, float* __restrict__ hfinal, unsigned* bar) {
  const int wg = blockIdx.x;  // 0..31
  const int c0 = wg * 16;
  const int tid = threadIdx.x;
  const int wave = tid >> 6, lane = tid & 63, lr = lane & 15, lg = lane >> 4;
  uint* U = (uint*)hpb;

  // preload bf16 weight fragments into registers (loop-invariant across all 128 steps)
  short8 wf0[16], wf1[16], wf2[16];
#pragma unroll
  for (int kk = 0; kk < 16; kk++) {
    short8 v0, v1, v2;
#pragma unroll
    for (int i = 0; i < 8; i++) {
      int k = kk * 32 + lg * 8 + i;
      v0[i] = (short)f2b(w_hh[(size_t)k * G3_ + 0 * H_ + c0 + lr]);
      v1[i] = (short)f2b(w_hh[(size_t)k * G3_ + 1 * H_ + c0 + lr]);
      v2[i] = (short)f2b(w_hh[(size_t)k * G3_ + 2 * H_ + c0 + lr]);
    }
    wf0[kk] = v0; wf1[kk] = v1; wf2[kk] = v2;
  }
  const float bh0 = b_hh[0 * H_ + c0 + lr], bh1 = b_hh[1 * H_ + c0 + lr], bh2 = b_hh[2 * H_ + c0 + lr];
  const int len0 = lengths[16 * wave + lg * 4 + 0];
  const int len1 = lengths[16 * wave + lg * 4 + 1];
  const int len2 = lengths[16 * wave + lg * 4 + 2];
  const int len3 = lengths[16 * wave + lg * 4 + 3];

#pragma unroll 1
  for (int t = 0; t < T_; t++) {
    f32x4 a0 = {}, a1 = {}, a2 = {};
    const int rowA = t * 32 + 16 * wave + lr;
#pragma unroll
    for (int kk = 0; kk < 16; kk++) {
      int ui = rowA * 256 + kk * 16 + lg * 4;
      union { uint u[4]; short8 s; } cv;
      cv.u[0] = __hip_atomic_load(U + ui + 0, __ATOMIC_RELAXED, __HIP_MEMORY_SCOPE_AGENT);
      cv.u[1] = __hip_atomic_load(U + ui + 1, __ATOMIC_RELAXED, __HIP_MEMORY_SCOPE_AGENT);
      cv.u[2] = __hip_atomic_load(U + ui + 2, __ATOMIC_RELAXED, __HIP_MEMORY_SCOPE_AGENT);
      cv.u[3] = __hip_atomic_load(U + ui + 3, __ATOMIC_RELAXED, __HIP_MEMORY_SCOPE_AGENT);
      a0 = __builtin_amdgcn_mfma_f32_16x16x32_bf16(cv.s, wf0[kk], a0, 0, 0, 0);
      a1 = __builtin_amdgcn_mfma_f32_16x16x32_bf16(cv.s, wf1[kk], a1, 0, 0, 0);
      a2 = __builtin_amdgcn_mfma_f32_16x16x32_bf16(cv.s, wf2[kk], a2, 0, 0, 0);
    }
#pragma unroll
    for (int r = 0; r < 4; r++) {
      int b = 16 * wave + lg * 4 + r;
      int row = t * 32 + b;
      int j = c0 + lr;
      const float* gir = gi + (size_t)row * G3_ + j;
      float Gr = a0[r] + bh0, Gz = a1[r] + bh1, Gn = a2[r] + bh2;
      float rr = sigmoid_f(gir[0] + Gr);
      float zz = sigmoid_f(gir[H_] + Gz);
      float nn = tanh_f(gir[2 * H_] + rr * Gn);
      float hp = hpf[(size_t)row * H_ + j];
      float hv = (1.f - zz) * nn + zz * hp;
      int len = (r == 0) ? len0 : ((r == 1) ? len1 : ((r == 2) ? len2 : len3));
      bool valid = t < len;
      float hx = valid ? hv : hp;
      hnew[(size_t)row * H_ + j] = hv;
      hidmem[((size_t)b * T_ + t) * H_ + j] = valid ? hv : 0.f;
      hpf[(size_t)(row + 32) * H_ + j] = hx;
      if (t == T_ - 1) hfinal[(size_t)b * H_ + j] = hx;
      uint hb = (uint)f2b(hx);
      uint ob = (uint)__shfl_xor((int)hb, 1, 64);
      if (!(lane & 1)) {
        uint packed = hb | (ob << 16);
        __hip_atomic_store(U + (size_t)(row + 32) * 256 + (j >> 1), packed,
                           __ATOMIC_RELAXED, __HIP_MEMORY_SCOPE_AGENT);
      }
    }
    // ---- grid barrier (sense via generation counter, agent scope) ----
    __syncthreads();
    if (tid == 0) {
      unsigned gen = __hip_atomic_load(bar + 1, __ATOMIC_RELAXED, __HIP_MEMORY_SCOPE_AGENT);
      unsigned arr = __hip_atomic_fetch_add(bar, 1u, __ATOMIC_ACQ_REL, __HIP_MEMORY_SCOPE_AGENT);
      if (arr == 31u) {
        __hip_atomic_store(bar, 0u, __ATOMIC_RELAXED, __HIP_MEMORY_SCOPE_AGENT);
        __hip_atomic_store(bar + 1, gen + 1u, __ATOMIC_RELEASE, __HIP_MEMORY_SCOPE_AGENT);
      } else {
        while (__hip_atomic_load(bar + 1, __ATOMIC_RELAXED, __HIP_MEMORY_SCOPE_AGENT) == gen) {
          __builtin_amdgcn_s_sleep(2);
        }
      }
      (void)__hip_atomic_load(bar + 1, __ATOMIC_ACQUIRE, __HIP_MEMORY_SCOPE_AGENT);
    }
    __syncthreads();
  }
}

// ---------------- MLP attention (scores + softmax + context), one block per (b,t) ----------------
__global__ __launch_bounds__(256) void attn_k(
    const float* __restrict__ qxk, const float* __restrict__ qh, const float* __restrict__ kq,
    const float* __restrict__ mk, const float* __restrict__ mem, const float* __restrict__ vvec,
    const int* __restrict__ slen, float* __restrict__ ctx) {
  __shared__ float qf[A_], vv[A_], sc[S_];
  int bx = blockIdx.x;  // b*T + t (b-major for mem L2 locality)
  int b = bx >> 7, t = bx & 127;
  int row = t * B_ + b;
  int tid = threadIdx.x;
  qf[tid] = qxk[(size_t)row * A_ + tid] + qh[(size_t)row * A_ + tid] + kq[b * A_ + tid];
  vv[tid] = vvec[tid];
  __syncthreads();
  int s = tid >> 2, q4 = tid & 3;
  const float* mkr = mk + ((size_t)(b * S_) + s) * A_;
  float part = 0.f;
  for (int a = q4 * 64; a < q4 * 64 + 64; a++) part += tanh_f(qf[a] + mkr[a]) * vv[a];
  part += __shfl_xor(part, 1, 64);
  part += __shfl_xor(part, 2, 64);
  if (q4 == 0) sc[s] = part;
  __syncthreads();
  if (tid < S_) {
    float v = (tid < slen[b]) ? sc[tid] : -1e9f;
    float mm = v;
    for (int off = 1; off < 64; off <<= 1) mm = fmaxf(mm, __shfl_xor(mm, off, 64));
    float e = __expf(v - mm);
    float ss = e;
    for (int off = 1; off < 64; off <<= 1) ss += __shfl_xor(ss, off, 64);
    sc[tid] = e / ss;
  }
  __syncthreads();
  float c0 = 0.f, c1 = 0.f;
  const float* mb = mem + (size_t)b * S_ * H_;
  for (int ss2 = 0; ss2 < S_; ss2++) {
    float w = sc[ss2];
    c0 += w * mb[ss2 * H_ + tid];
    c1 += w * mb[ss2 * H_ + tid + 256];
  }
  ctx[(size_t)row * H_ + tid] = c0;
  ctx[(size_t)row * H_ + tid + 256] = c1;
}

// ---------------- assemble out_in (bf16, masked) ----------------
__global__ __launch_bounds__(256) void assemble_k(
    const ushort* __restrict__ xbf, const float* __restrict__ hnew,
    const float* __restrict__ knowledge, const float* __restrict__ ctxs,
    const float* __restrict__ ctxc, const int* __restrict__ lengths,
    ushort* __restrict__ outin) {
  int r = blockIdx.x;
  int t = r >> 5, b = r & 31;
  bool valid = t < lengths[b];
  int tid = threadIdx.x;
  ushort* dst = outin + (size_t)r * OUTIN_;
#pragma unroll
  for (int kblk = 0; kblk < 9; kblk++) {
    int i = kblk * 256 + tid;
    ushort v;
    if (i < E_)               v = xbf[(size_t)r * E_ + i];
    else if (i < E_ + H_)     v = f2b(hnew[(size_t)r * H_ + i - E_]);
    else if (i < E_ + 2 * H_) v = f2b(knowledge[b * H_ + i - (E_ + H_)]);
    else if (i < E_ + 3 * H_) v = f2b(ctxs[(size_t)r * H_ + i - (E_ + 2 * H_)]);
    else                      v = f2b(ctxc[(size_t)r * H_ + i - (E_ + 3 * H_)]);
    dst[i] = valid ? v : (ushort)0;
  }
}

// ---------------- in-place row log_softmax over V ----------------
__global__ __launch_bounds__(256) void logsoftmax_k(float* __restrict__ logits) {
  __shared__ float red[8];
  float* row = logits + (size_t)blockIdx.x * V_;
  float4* r4 = (float4*)row;
  int tid = threadIdx.x;
  float m = -3.4e38f;
  for (int i = tid; i < V_ / 4; i += 256) {
    float4 v = r4[i];
    m = fmaxf(m, fmaxf(fmaxf(v.x, v.y), fmaxf(v.z, v.w)));
  }
  for (int off = 1; off < 64; off <<= 1) m = fmaxf(m, __shfl_xor(m, off, 64));
  if ((tid & 63) == 0) red[tid >> 6] = m;
  __syncthreads();
  m = fmaxf(fmaxf(red[0], red[1]), fmaxf(red[2], red[3]));
  float s = 0.f;
  for (int i = tid; i < V_ / 4; i += 256) {
    float4 v = r4[i];
    s += __expf(v.x - m) + __expf(v.y - m) + __expf(v.z - m) + __expf(v.w - m);
  }
  for (int off = 1; off < 64; off <<= 1) s += __shfl_xor(s, off, 64);
  if ((tid & 63) == 0) red[4 + (tid >> 6)] = s;
  __syncthreads();
  s = red[4] + red[5] + red[6] + red[7];
  float lse = m + __logf(s);
  for (int i = tid; i < V_ / 4; i += 256) {
    float4 v = r4[i];
    v.x -= lse; v.y -= lse; v.z -= lse; v.w -= lse;
    r4[i] = v;
  }
}

extern "C" void kernel_launch(void* const* d_in, const int* in_sizes, int n_in,
                              void* d_out, int out_size, void* d_ws, size_t ws_size,
                              hipStream_t stream) {
  const int*   tokens    = (const int*)  d_in[0];
  const int*   lengths   = (const int*)  d_in[1];
  const float* hidden0   = (const float*)d_in[2];
  const float* knowledge = (const float*)d_in[3];
  const float* src_mem   = (const float*)d_in[4];
  const int*   src_len   = (const int*)  d_in[5];
  const float* cue_mem   = (const float*)d_in[6];
  const int*   cue_len   = (const int*)  d_in[7];
  const float* emb       = (const float*)d_in[8];
  const float* w_ih      = (const float*)d_in[9];
  const float* w_hh      = (const float*)d_in[10];
  const float* b_ih      = (const float*)d_in[11];
  const float* b_hh      = (const float*)d_in[12];
  const float* src_wq    = (const float*)d_in[13];
  const float* src_bq    = (const float*)d_in[14];
  const float* src_wm    = (const float*)d_in[15];
  const float* src_v     = (const float*)d_in[16];
  const float* cue_wq    = (const float*)d_in[17];
  const float* cue_bq    = (const float*)d_in[18];
  const float* cue_wm    = (const float*)d_in[19];
  const float* cue_v     = (const float*)d_in[20];
  const float* w_out1    = (const float*)d_in[21];
  const float* b_out1    = (const float*)d_in[22];
  const float* w_out2    = (const float*)d_in[23];
  const float* b_out2    = (const float*)d_in[24];

  float* out_lp = (float*)d_out;                    // (B,T,V)
  float* out_hm = out_lp + (size_t)M_ * V_;         // (B,T,H)
  float* out_hf = out_hm + (size_t)M_ * H_;         // (B,H)

  // ---- scratch carved out of the (not-yet-written) logits region of d_out ----
  // every buffer below is dead before the logits GEMM overwrites this region
  char* scb = (char*)d_out;
  size_t off = 0;
  auto alloc = [&](size_t bytes) -> void* {
    void* p = scb + off;
    off = (off + bytes + 255) & ~(size_t)255;
    return p;
  };
  float*  GI    = (float*) alloc((size_t)M_ * G3_ * 4);
  float*  QXKs  = (float*) alloc((size_t)M_ * A_ * 4);
  float*  QXKc  = (float*) alloc((size_t)M_ * A_ * 4);
  float*  QHs   = (float*) alloc((size_t)M_ * A_ * 4);
  float*  QHc   = (float*) alloc((size_t)M_ * A_ * 4);
  float*  CTXs  = (float*) alloc((size_t)M_ * H_ * 4);
  float*  CTXc  = (float*) alloc((size_t)M_ * H_ * 4);
  float*  HNEW  = (float*) alloc((size_t)M_ * H_ * 4);
  ushort* OUTIN = (ushort*)alloc((size_t)M_ * OUTIN_ * 2);
  ushort* XBF   = (ushort*)alloc((size_t)M_ * E_ * 2);
  ushort* WIHT  = (ushort*)alloc((size_t)G3_ * E_ * 2);
  ushort* WQXTs = (ushort*)alloc((size_t)A_ * E_ * 2);
  ushort* WQXTc = (ushort*)alloc((size_t)A_ * E_ * 2);
  ushort* WQHTs = (ushort*)alloc((size_t)A_ * H_ * 2);
  ushort* WQHTc = (ushort*)alloc((size_t)A_ * H_ * 2);
  ushort* WMTs  = (ushort*)alloc((size_t)A_ * H_ * 2);
  ushort* WMTc  = (ushort*)alloc((size_t)A_ * H_ * 2);
  ushort* WO1T  = (ushort*)alloc((size_t)H_ * OUTIN_ * 2);
  ushort* MEMBs = (ushort*)alloc((size_t)B_ * S_ * H_ * 2);
  ushort* MEMBc = (ushort*)alloc((size_t)B_ * S_ * H_ * 2);
  float*  MKs   = (float*) alloc((size_t)B_ * S_ * A_ * 4);
  float*  MKc   = (float*) alloc((size_t)B_ * S_ * A_ * 4);
  float*  KQs   = (float*) alloc((size_t)B_ * A_ * 4);
  float*  KQc   = (float*) alloc((size_t)B_ * A_ * 4);
  float*  HPF   = (float*) alloc((size_t)(T_ + 1) * B_ * H_ * 4);  // carried state slabs
  ushort* HPB   = (ushort*)alloc((size_t)(T_ + 1) * B_ * H_ * 2);  // bf16 mirror for MFMA

  // ---- d_ws: only what must survive into the logits GEMM ----
  unsigned* BAR = (unsigned*)d_ws;
  ushort* WO2T = (ushort*)((char*)d_ws + 256);                       // (V x H) bf16
  ushort* HID1 = (ushort*)((char*)d_ws + 256 + (size_t)V_ * H_ * 2); // (M x H) bf16

  dim3 blk(256);
  hipMemsetAsync(BAR, 0, 8, stream);

  // weight transposes (f32 KxN -> bf16 NxK)
  transpose_k<<<dim3(G3_ / 64, E_ / 64), blk, 0, stream>>>(w_ih, WIHT, E_, G3_);
  transpose_k<<<dim3(A_ / 64, E_ / 64), blk, 0, stream>>>(src_wq, WQXTs, E_, A_);
  transpose_k<<<dim3(A_ / 64, H_ / 64), blk, 0, stream>>>(src_wq + (size_t)E_ * A_, WQHTs, H_, A_);
  transpose_k<<<dim3(A_ / 64, E_ / 64), blk, 0, stream>>>(cue_wq, WQXTc, E_, A_);
  transpose_k<<<dim3(A_ / 64, H_ / 64), blk, 0, stream>>>(cue_wq + (size_t)E_ * A_, WQHTc, H_, A_);
  transpose_k<<<dim3(A_ / 64, H_ / 64), blk, 0, stream>>>(src_wm, WMTs, H_, A_);
  transpose_k<<<dim3(A_ / 64, H_ / 64), blk, 0, stream>>>(cue_wm, WMTc, H_, A_);
  transpose_k<<<dim3(H_ / 64, OUTIN_ / 64), blk, 0, stream>>>(w_out1, WO1T, OUTIN_, H_);
  transpose_k<<<dim3(V_ / 64, H_ / 64), blk, 0, stream>>>(w_out2, WO2T, H_, V_);
  convert_k<<<(B_ * S_ * H_ + 255) / 256, blk, 0, stream>>>(src_mem, MEMBs, B_ * S_ * H_);
  convert_k<<<(B_ * S_ * H_ + 255) / 256, blk, 0, stream>>>(cue_mem, MEMBc, B_ * S_ * H_);

  gather_k<<<M_, blk, 0, stream>>>(tokens, emb, XBF);
  kq_k<<<B_, blk, 0, stream>>>(knowledge, src_wq, src_bq, KQs);
  kq_k<<<B_, blk, 0, stream>>>(knowledge, cue_wq, cue_bq, KQc);

  // precompute GEMMs
  gemm_bt<0, 0, 1><<<dim3(G3_ / 128, M_ / 128), blk, 0, stream>>>(XBF, WIHT, b_ih, GI, M_, G3_, E_);
  gemm_bt<0, 0, 0><<<dim3(A_ / 128, M_ / 128), blk, 0, stream>>>(XBF, WQXTs, nullptr, QXKs, M_, A_, E_);
  gemm_bt<0, 0, 0><<<dim3(A_ / 128, M_ / 128), blk, 0, stream>>>(XBF, WQXTc, nullptr, QXKc, M_, A_, E_);
  gemm_bt<0, 0, 0><<<dim3(A_ / 128, (B_ * S_) / 128), blk, 0, stream>>>(MEMBs, WMTs, nullptr, MKs, B_ * S_, A_, H_);
  gemm_bt<0, 0, 0><<<dim3(A_ / 128, (B_ * S_) / 128), blk, 0, stream>>>(MEMBc, WMTc, nullptr, MKc, B_ * S_, A_, H_);

  // sequential GRU scan
  inith_k<<<(B_ * H_) / 256, blk, 0, stream>>>(hidden0, HPF, HPB);
  scan_k<<<32, dim3(128), 0, stream>>>(w_hh, b_hh, GI, lengths, HPF, HPB, HNEW, out_hm, out_hf, BAR);

  // parallel attention over all (b,t)
  gemm_bt<0, 0, 0><<<dim3(A_ / 128, M_ / 128), blk, 0, stream>>>(HPB, WQHTs, nullptr, QHs, M_, A_, H_);
  gemm_bt<0, 0, 0><<<dim3(A_ / 128, M_ / 128), blk, 0, stream>>>(HPB, WQHTc, nullptr, QHc, M_, A_, H_);
  attn_k<<<M_, blk, 0, stream>>>(QXKs, QHs, KQs, MKs, src_mem, src_v, src_len, CTXs);
  attn_k<<<M_, blk, 0, stream>>>(QXKc, QHc, KQc, MKc, cue_mem, cue_v, cue_len, CTXc);

  // output head
  assemble_k<<<M_, blk, 0, stream>>>(XBF, HNEW, knowledge, CTXs, CTXc, lengths, OUTIN);
  gemm_bt<1, 0, 1><<<dim3(H_ / 128, M_ / 128), blk, 0, stream>>>(OUTIN, WO1T, b_out1, HID1, M_, H_, OUTIN_);
  gemm_bt<0, 1, 1><<<dim3(V_ / 128, M_ / 128), blk, 0, stream>>>(HID1, WO2T, b_out2, out_lp, M_, V_, H_);
  logsoftmax_k<<<M_, blk, 0, stream>>>(out_lp);
}